// Round 17
// baseline (740.934 us; speedup 1.0000x reference)
//
#include <hip/hip_runtime.h>

#define B_ 256
#define T_ 128
#define E_ 512
#define H_ 512
#define NG 2048   // 4*H_
#define NB 256    // persistent blocks
#define NT 512    // threads per block (8 waves)

typedef __attribute__((ext_vector_type(8))) short bf16x8;
typedef __attribute__((ext_vector_type(4))) float f32x4;
typedef __attribute__((ext_vector_type(4))) float float4v;
typedef unsigned long long u64;

__device__ __forceinline__ short f2bf(float f) {
  union { float f; unsigned u; } x; x.f = f;
  unsigned r = x.u + 0x7FFFu + ((x.u >> 16) & 1u);  // RNE
  return (short)(r >> 16);
}
__device__ __forceinline__ float bf2f(short s) {
  union { unsigned u; float f; } x;
  x.u = ((unsigned)(unsigned short)s) << 16; return x.f;
}
__device__ __forceinline__ float sigm(float x) { return 1.0f / (1.0f + __expf(-x)); }
__device__ __forceinline__ float tanh_(float x) {
  float cx = fminf(fmaxf(x, -9.f), 9.f);
  float e = __expf(2.f * cx);
  return (e - 1.f) / (e + 1.f);
}

// ---- Wt[j][k] = bf16( k<512 ? Wx[k][j] : Uh[k-512][j] )
__global__ __launch_bounds__(256) void prep_w(const float* __restrict__ Wx,
                                              const float* __restrict__ Uh,
                                              short* __restrict__ Wt) {
  __shared__ float tile[64][65];
  const int k0 = blockIdx.x * 64;   // 16 blocks
  const int j0 = blockIdx.y * 64;   // 32 blocks
  const int tx = threadIdx.x & 63, ty = threadIdx.x >> 6;
#pragma unroll
  for (int r = 0; r < 16; ++r) {
    int k = k0 + r * 4 + ty;
    float v = (k < 512) ? Wx[(size_t)k * NG + j0 + tx]
                        : Uh[(size_t)(k - 512) * NG + j0 + tx];
    tile[r * 4 + ty][tx] = v;
  }
  __syncthreads();
#pragma unroll
  for (int r = 0; r < 16; ++r) {
    int j = j0 + r * 4 + ty;
    Wt[(size_t)j * 1024 + k0 + tx] = f2bf(tile[tx][r * 4 + ty]);
  }
}

// ---- persistent kernel: all 128 LSTM steps.  FAN-IN-16 GEOMETRY (R14/R15,
// proven 624 us) with the embedding gather FUSED into the x-waves:
// kq0/1 read emb (fp32, read-only input -> plain cached loads are safe; the
// 64 MB table is L3-resident after first touch) and convert to bf16 in
// registers. This work sits in kq0/1's ~4 us of barrier slack — off the
// critical path, which runs through kq2/3's h exchange. Eliminates the
// stage_x kernel (96 MB HBM) and the 32 MB xs buffer.
// grid 256 = 16 m-groups (mg = bid>>4, 16 batch rows) x 16 j-tiles (jt =
// bid&15, 32 hidden cols). Waves (kq = wid>>1, jh = wid&1).
// Protocol (R10, proven): phase A computes; partials (kq0,1,3) -> parity LDS,
// lgkmcnt(0), raw s_barrier; phase B: kq2 waves reduce in regs + gates (c in
// regs) + packed-u32 h store + vmcnt(0) ACK + per-wave flag (one 128-B line
// each). Readers poll 16 flag lines (8 writer blocks x 2 publisher waves),
// then one bulk u64 load pass.
// Overwrite safety (2 buffers): flag=t+1 from Y implies Y passed barrier(t),
// hence Y consumed h_{t-1}; X stores h_{t+1} (same buffer) only after its kq2
// AND kq3 saw all slice flags >= t+1 (barrier-ordered). Flags zeroed per launch.
__global__ __launch_bounds__(NT, 2) void lstm_all(
    const int* __restrict__ captions,   // [B][T]
    const float* __restrict__ emb,      // [VOCAB][E] fp32, read-only
    const short* __restrict__ Wt,       // [2048][1024] bf16
    const float* __restrict__ bx, const float* __restrict__ bu,
    unsigned* __restrict__ hb0, unsigned* __restrict__ hb1,
    unsigned* __restrict__ flags) {     // [16 mg][2 jh][16 jt] stride 32 uints
  // [parity][slot(kq0,kq1,kq3)][jh][gate][l4][l15] of f32x4 -> 48 KB
  __shared__ f32x4 part[2][3][2][4][4][16];

  const int tid = threadIdx.x;
  const int wid = tid >> 6, lane = tid & 63;
  const int l15 = lane & 15, l4 = lane >> 4;
  const int kq = wid >> 1, jh = wid & 1;
  const int mg = blockIdx.x >> 4, jt = blockIdx.x & 15;
  const int j0 = jt * 32;                 // 32 hidden cols per block
  const int rA = mg * 16 + l15;           // 16 batch rows per block

  // ---- persistent B fragments, pinned on-chip (VGPR/AGPR)
  bf16x8 bfr[4][8];
#pragma unroll
  for (int g = 0; g < 4; ++g) {
    const short* wp = Wt + (size_t)(g * 512 + j0 + jh * 16 + l15) * 1024
                         + kq * 256 + l4 * 8;
#pragma unroll
    for (int ks = 0; ks < 8; ++ks)
      bfr[g][ks] = *(const bf16x8*)(wp + ks * 32);
  }
#pragma unroll
  for (int g = 0; g < 4; ++g)
#pragma unroll
    for (int ks = 0; ks < 8; ++ks)
      asm volatile("" : "+v"(bfr[g][ks]));   // sever rematerialization

  // ---- kq2 gate constants: lane owns col J, rows l4*4+r (4 cells)
  const int J = j0 + jh * 16 + l15;
  const float bi  = bx[J] + bu[J];
  const float bf_ = bx[512 + J] + bu[512 + J];
  const float bo  = bx[1024 + J] + bu[1024 + J];
  const float bg  = bx[1536 + J] + bu[1536 + J];
  float c_reg[4] = {0.f, 0.f, 0.f, 0.f};

  unsigned* fl = flags + mg * 1024;   // flag (jh,jt) at fl[(jh*16+jt)*32]

  // x-wave constants: this lane's emb base for its row & K-quarter
  const float* ebase = emb + (size_t)kq * 256 + l4 * 8;   // + tok*E_ per step

  for (int t = 0; t < T_; ++t) {
    const int tp = t & 1;
    unsigned* hout = tp ? hb1 : hb0;
    const unsigned* hin = tp ? hb0 : hb1;   // h_{t-1} in buffer (t-1)&1

    f32x4 acc[4] = {{0,0,0,0},{0,0,0,0},{0,0,0,0},{0,0,0,0}};

    if (kq < 2) {
      // ---- x half of K: gather emb[tok] fp32 -> bf16 frags in registers
      const int tok = captions[rA * T_ + t];       // cached; same line 32 steps
      const float* ep = ebase + (size_t)tok * E_;
      bf16x8 af[8];
#pragma unroll
      for (int ks = 0; ks < 8; ++ks) {
        float4v v0 = *(const float4v*)(ep + ks * 32);
        float4v v1 = *(const float4v*)(ep + ks * 32 + 4);
        bf16x8 a;
        a[0] = f2bf(v0[0]); a[1] = f2bf(v0[1]); a[2] = f2bf(v0[2]); a[3] = f2bf(v0[3]);
        a[4] = f2bf(v1[0]); a[5] = f2bf(v1[1]); a[6] = f2bf(v1[2]); a[7] = f2bf(v1[3]);
        af[ks] = tok ? a : (bf16x8)0;              // padding_idx=0 -> zero row
      }
#pragma unroll
      for (int ks = 0; ks < 8; ++ks)
#pragma unroll
        for (int g = 0; g < 4; ++g)
          acc[g] = __builtin_amdgcn_mfma_f32_16x16x32_bf16(af[ks], bfr[g][ks], acc[g], 0, 0, 0);
    } else if (t > 0) {
      // ---- poll the 16 publisher flags of this slice: 8 writer blocks x 2 jh
      const unsigned thr = (unsigned)t;
      const int jtp = (kq - 2) * 8 + (lane >> 1 & 7);   // writer j-tile
      const int jhp = lane & 1;                          // writer jh wave
      const unsigned* myfl = fl + (jhp * 16 + jtp) * 32;
      unsigned v = __hip_atomic_load(myfl, __ATOMIC_RELAXED, __HIP_MEMORY_SCOPE_AGENT);
      int spin = 0;
      while (!__all((int)((lane >= 16) | (v >= thr)))) {
        if (spin++ < 4) __builtin_amdgcn_s_sleep(1);
        else            __builtin_amdgcn_s_sleep(2);
        v = __hip_atomic_load(myfl, __ATOMIC_RELAXED, __HIP_MEMORY_SCOPE_AGENT);
      }
      asm volatile("" ::: "memory");
      // ---- one bulk load pass (flags are ack-gated: data valid), then MFMA
      const u64* hp = (const u64*)hin + (size_t)rA * 128 + (kq - 2) * 64 + l4 * 2;
      u64 w[16];
#pragma unroll
      for (int ks = 0; ks < 8; ++ks) {
        w[ks * 2]     = __hip_atomic_load(hp + ks * 8,     __ATOMIC_RELAXED, __HIP_MEMORY_SCOPE_AGENT);
        w[ks * 2 + 1] = __hip_atomic_load(hp + ks * 8 + 1, __ATOMIC_RELAXED, __HIP_MEMORY_SCOPE_AGENT);
      }
#pragma unroll
      for (int ks = 0; ks < 8; ++ks) {
        union { bf16x8 v; unsigned u[4]; } fa;
        fa.u[0] = (unsigned)w[ks * 2];
        fa.u[1] = (unsigned)(w[ks * 2] >> 32);
        fa.u[2] = (unsigned)w[ks * 2 + 1];
        fa.u[3] = (unsigned)(w[ks * 2 + 1] >> 32);
#pragma unroll
        for (int g = 0; g < 4; ++g)
          acc[g] = __builtin_amdgcn_mfma_f32_16x16x32_bf16(fa.v, bfr[g][ks], acc[g], 0, 0, 0);
      }
    }
    // (kq>=2, t==0: h_{-1}=0 -> acc stays 0)

    // ---- partials to parity LDS slot (one ds_write_b128 per gate);
    //      kq2 keeps its partial in registers
    if (kq != 2) {
      const int slot = (kq == 3) ? 2 : kq;
#pragma unroll
      for (int g = 0; g < 4; ++g)
        part[tp][slot][jh][g][l4][l15] = acc[g];
    }
    asm volatile("s_waitcnt lgkmcnt(0)" ::: "memory");
    __builtin_amdgcn_s_barrier();               // raw barrier: no vmcnt drain

    // ---- phase B: kq2 waves finalize; others run ahead into t+1
    if (kq == 2) {
#pragma unroll
      for (int g = 0; g < 4; ++g)
        acc[g] += part[tp][0][jh][g][l4][l15]
                + part[tp][1][jh][g][l4][l15]
                + part[tp][2][jh][g][l4][l15];
      unsigned hw[4];
#pragma unroll
      for (int r = 0; r < 4; ++r) {
        float iv = acc[0][r] + bi, fv = acc[1][r] + bf_;
        float ov = acc[2][r] + bo, gv = acc[3][r] + bg;
        float cn = sigm(fv) * c_reg[r] + sigm(iv) * tanh_(gv);
        c_reg[r] = cn;
        hw[r] = (unsigned)(unsigned short)f2bf(sigm(ov) * tanh_(cn));
      }
#pragma unroll
      for (int r = 0; r < 4; ++r) {
        unsigned other = (unsigned)__shfl_xor((int)hw[r], 1, 64);
        if (!(l15 & 1)) {
          const int R = mg * 16 + l4 * 4 + r;
          __hip_atomic_store(hout + (size_t)R * 256 + (J >> 1),
                             hw[r] | (other << 16),
                             __ATOMIC_RELAXED, __HIP_MEMORY_SCOPE_AGENT);
        }
      }
      // ACK then flag: readers that see the flag see the data (R10 protocol).
      asm volatile("s_waitcnt vmcnt(0)" ::: "memory");
      if (lane == 0)
        __hip_atomic_store(fl + (jh * 16 + jt) * 32, (unsigned)(t + 1),
                           __ATOMIC_RELAXED, __HIP_MEMORY_SCOPE_AGENT);
    }
  }
}

// ---- out[b,:] = normalize( h_last[b,:] @ fcW + fcb ); h packed u32{2xbf16}.
// 4 rows per block (64 blocks): fcW read once per 4 rows.
__global__ __launch_bounds__(256) void final_fc(const unsigned* __restrict__ h,
                                                const float* __restrict__ fcW,
                                                const float* __restrict__ fcb,
                                                float* __restrict__ out) {
  const int b0 = blockIdx.x * 4, tid = threadIdx.x;
  __shared__ float hrow[4][512];
  __shared__ float red[4][256];
  for (int i = tid; i < 1024; i += 256) {
    unsigned w = h[(size_t)(b0 + (i >> 8)) * 256 + (i & 255)];
    hrow[i >> 8][(i & 255) * 2]     = bf2f((short)(w & 0xFFFF));
    hrow[i >> 8][(i & 255) * 2 + 1] = bf2f((short)(w >> 16));
  }
  __syncthreads();
  float a0[4], a1[4];
#pragma unroll
  for (int r = 0; r < 4; ++r) { a0[r] = fcb[tid]; a1[r] = fcb[tid + 256]; }
  for (int k = 0; k < 512; ++k) {
    const float w0 = fcW[(size_t)k * 512 + tid];
    const float w1 = fcW[(size_t)k * 512 + tid + 256];
#pragma unroll
    for (int r = 0; r < 4; ++r) {
      a0[r] += hrow[r][k] * w0;
      a1[r] += hrow[r][k] * w1;
    }
  }
#pragma unroll
  for (int r = 0; r < 4; ++r) red[r][tid] = a0[r] * a0[r] + a1[r] * a1[r];
  __syncthreads();
  for (int s = 128; s > 0; s >>= 1) {
    if (tid < s) {
#pragma unroll
      for (int r = 0; r < 4; ++r) red[r][tid] += red[r][tid + s];
    }
    __syncthreads();
  }
#pragma unroll
  for (int r = 0; r < 4; ++r) {
    const float scale = 1.0f / fmaxf(sqrtf(red[r][0]), 1e-12f);
    out[(size_t)(b0 + r) * 512 + tid]       = a0[r] * scale;
    out[(size_t)(b0 + r) * 512 + tid + 256] = a1[r] * scale;
  }
}

extern "C" void kernel_launch(void* const* d_in, const int* in_sizes, int n_in,
                              void* d_out, int out_size, void* d_ws, size_t ws_size,
                              hipStream_t stream) {
  const int*   captions = (const int*)d_in[0];
  const float* emb      = (const float*)d_in[1];
  const float* Wx       = (const float*)d_in[2];
  const float* bx       = (const float*)d_in[3];
  const float* Uh       = (const float*)d_in[4];
  const float* bu       = (const float*)d_in[5];
  const float* fcW      = (const float*)d_in[6];
  const float* fcb      = (const float*)d_in[7];
  float* out = (float*)d_out;

  char* ws = (char*)d_ws;
  size_t off = 0;
  auto alloc = [&](size_t bytes) {
    char* p = ws + off;
    off += (bytes + 255) & ~(size_t)255;
    return p;
  };
  short*    Wt    = (short*)alloc((size_t)NG * 1024 * 2);     // 4 MB
  unsigned* hb0   = (unsigned*)alloc((size_t)B_ * 256 * 4);   // 256 KB packed
  unsigned* hb1   = (unsigned*)alloc((size_t)B_ * 256 * 4);
  unsigned* flags = (unsigned*)alloc(16 * 2 * 16 * 32 * 4);   // 64 KB strided

  // flags gate all h reads -> zero every launch (graph replay safe)
  hipMemsetAsync(flags, 0, 16 * 2 * 16 * 32 * 4, stream);

  prep_w<<<dim3(16, 32), 256, 0, stream>>>(Wx, Uh, Wt);

  void* kargs[] = {(void*)&captions, (void*)&emb, (void*)&Wt,
                   (void*)&bx, (void*)&bu,
                   (void*)&hb0, (void*)&hb1, (void*)&flags};
  hipLaunchCooperativeKernel((const void*)lstm_all, dim3(NB), dim3(NT),
                             kargs, 0, stream);

  // t=127 wrote buffer 127&1 = hb1
  final_fc<<<64, 256, 0, stream>>>(hb1, fcW, fcb, out);
}

// Round 18
// 686.954 us; speedup vs baseline: 1.0786x; 1.0786x over previous
//
#include <hip/hip_runtime.h>

#define B_ 256
#define T_ 128
#define E_ 512
#define H_ 512
#define NG 2048   // 4*H_
#define NB 256    // persistent blocks
#define NT 512    // threads per block (8 waves)

typedef __attribute__((ext_vector_type(8))) short bf16x8;
typedef __attribute__((ext_vector_type(4))) float f32x4;
typedef unsigned long long u64;

__device__ __forceinline__ short f2bf(float f) {
  union { float f; unsigned u; } x; x.f = f;
  unsigned r = x.u + 0x7FFFu + ((x.u >> 16) & 1u);  // RNE
  return (short)(r >> 16);
}
__device__ __forceinline__ float bf2f(short s) {
  union { unsigned u; float f; } x;
  x.u = ((unsigned)(unsigned short)s) << 16; return x.f;
}
__device__ __forceinline__ float sigm(float x) { return 1.0f / (1.0f + __expf(-x)); }
__device__ __forceinline__ float tanh_(float x) {
  float cx = fminf(fmaxf(x, -9.f), 9.f);
  float e = __expf(2.f * cx);
  return (e - 1.f) / (e + 1.f);
}

// ---- merged prologue: blocks 0..511 transpose weights (Wt[j][k] = bf16(
// k<512 ? Wx[k][j] : Uh[k-512][j])); blocks 512..2559 grid-stride the
// embedding gather (xs[t][b][e] = bf16(emb[captions[b][t]][e]), zero row for
// padding token 0). The two halves are independent; merging removes one
// dispatch + launch gap from the serial prologue.
__global__ __launch_bounds__(256) void prologue(const float* __restrict__ Wx,
                                                const float* __restrict__ Uh,
                                                const int* __restrict__ captions,
                                                const float* __restrict__ emb,
                                                short* __restrict__ Wt,
                                                short* __restrict__ xs) {
  const int p = blockIdx.x;
  if (p < 512) {
    // ---- prep_w part
    __shared__ float tile[64][65];
    const int k0 = (p & 15) * 64;
    const int j0 = (p >> 4) * 64;
    const int tx = threadIdx.x & 63, ty = threadIdx.x >> 6;
#pragma unroll
    for (int r = 0; r < 16; ++r) {
      int k = k0 + r * 4 + ty;
      float v = (k < 512) ? Wx[(size_t)k * NG + j0 + tx]
                          : Uh[(size_t)(k - 512) * NG + j0 + tx];
      tile[r * 4 + ty][tx] = v;
    }
    __syncthreads();
#pragma unroll
    for (int r = 0; r < 16; ++r) {
      int j = j0 + r * 4 + ty;
      Wt[(size_t)j * 1024 + k0 + tx] = f2bf(tile[tx][r * 4 + ty]);
    }
  } else {
    // ---- stage_x part: 2048 blocks cover 32768 (t,b) pairs
    for (int bid = p - 512; bid < T_ * B_; bid += 2048) {
      const int t = bid >> 8, b = bid & 255;
      const int tok = captions[b * T_ + t];
      short* o = xs + (size_t)bid * E_;
      const float* src = emb + (size_t)tok * E_;
      int e0 = threadIdx.x, e1 = threadIdx.x + 256;
      if (tok) { o[e0] = f2bf(src[e0]); o[e1] = f2bf(src[e1]); }
      else     { o[e0] = 0;             o[e1] = 0; }
    }
  }
}

// ---- persistent kernel: all 128 LSTM steps.  FAN-IN-16 GEOMETRY (R14/R15,
// proven 624 us loop). grid 256 = 16 m-groups (mg = bid>>4, 16 batch rows) x
// 16 j-tiles (jt = bid&15, 32 hidden cols). Consecutive bids per group ->
// spread across XCDs (fabric load-balanced). Waves (kq = wid>>1, jh = wid&1):
// kq0/1 = x K-halves, kq2/3 = h K-halves; jh = 16-col hidden sub-slice.
// Protocol (R10, proven): phase A computes; partials (kq0,1,3) -> parity LDS,
// lgkmcnt(0), raw s_barrier; phase B: kq2 waves reduce in regs + gates (c in
// regs) + packed-u32 h store + vmcnt(0) ACK + per-wave flag (one 128-B line
// each). Readers poll 16 flag lines (8 writer blocks x 2 publisher waves),
// then one bulk u64 load pass.
// Overwrite safety (2 buffers): flag=t+1 from Y implies Y passed barrier(t),
// hence Y consumed h_{t-1}; X stores h_{t+1} (same buffer) only after its kq2
// AND kq3 saw all slice flags >= t+1 (barrier-ordered). Flags zeroed per launch.
__global__ __launch_bounds__(NT, 2) void lstm_all(
    const short* __restrict__ xs,   // [T][B][E] bf16
    const short* __restrict__ Wt,   // [2048][1024] bf16
    const float* __restrict__ bx, const float* __restrict__ bu,
    unsigned* __restrict__ hb0, unsigned* __restrict__ hb1,
    unsigned* __restrict__ flags) { // [16 mg][2 jh][16 jt] stride 32 uints
  // [parity][slot(kq0,kq1,kq3)][jh][gate][l4][l15] of f32x4 -> 48 KB
  __shared__ f32x4 part[2][3][2][4][4][16];

  const int tid = threadIdx.x;
  const int wid = tid >> 6, lane = tid & 63;
  const int l15 = lane & 15, l4 = lane >> 4;
  const int kq = wid >> 1, jh = wid & 1;
  const int mg = blockIdx.x >> 4, jt = blockIdx.x & 15;
  const int j0 = jt * 32;                 // 32 hidden cols per block
  const int rA = mg * 16 + l15;           // 16 batch rows per block

  // ---- persistent B fragments, pinned on-chip (VGPR/AGPR)
  bf16x8 bfr[4][8];
#pragma unroll
  for (int g = 0; g < 4; ++g) {
    const short* wp = Wt + (size_t)(g * 512 + j0 + jh * 16 + l15) * 1024
                         + kq * 256 + l4 * 8;
#pragma unroll
    for (int ks = 0; ks < 8; ++ks)
      bfr[g][ks] = *(const bf16x8*)(wp + ks * 32);
  }
#pragma unroll
  for (int g = 0; g < 4; ++g)
#pragma unroll
    for (int ks = 0; ks < 8; ++ks)
      asm volatile("" : "+v"(bfr[g][ks]));   // sever rematerialization

  // ---- kq2 gate constants: lane owns col J, rows l4*4+r (4 cells)
  const int J = j0 + jh * 16 + l15;
  const float bi  = bx[J] + bu[J];
  const float bf_ = bx[512 + J] + bu[512 + J];
  const float bo  = bx[1024 + J] + bu[1024 + J];
  const float bg  = bx[1536 + J] + bu[1536 + J];
  float c_reg[4] = {0.f, 0.f, 0.f, 0.f};

  unsigned* fl = flags + mg * 1024;   // flag (jh,jt) at fl[(jh*16+jt)*32]

  for (int t = 0; t < T_; ++t) {
    const int tp = t & 1;
    unsigned* hout = tp ? hb1 : hb0;
    const unsigned* hin = tp ? hb0 : hb1;   // h_{t-1} in buffer (t-1)&1

    f32x4 acc[4] = {{0,0,0,0},{0,0,0,0},{0,0,0,0},{0,0,0,0}};

    if (kq < 2) {
      // ---- x half of K (staged bf16, always ready)
      const short* ab = xs + ((size_t)t * B_ + rA) * E_ + kq * 256 + l4 * 8;
      bf16x8 af[8];
#pragma unroll
      for (int ks = 0; ks < 8; ++ks) af[ks] = *(const bf16x8*)(ab + ks * 32);
#pragma unroll
      for (int ks = 0; ks < 8; ++ks)
#pragma unroll
        for (int g = 0; g < 4; ++g)
          acc[g] = __builtin_amdgcn_mfma_f32_16x16x32_bf16(af[ks], bfr[g][ks], acc[g], 0, 0, 0);
    } else if (t > 0) {
      // ---- poll the 16 publisher flags of this slice: 8 writer blocks x 2 jh
      const unsigned thr = (unsigned)t;
      const int jtp = (kq - 2) * 8 + (lane >> 1 & 7);   // writer j-tile
      const int jhp = lane & 1;                          // writer jh wave
      const unsigned* myfl = fl + (jhp * 16 + jtp) * 32;
      unsigned v = __hip_atomic_load(myfl, __ATOMIC_RELAXED, __HIP_MEMORY_SCOPE_AGENT);
      int spin = 0;
      while (!__all((int)((lane >= 16) | (v >= thr)))) {
        if (spin++ < 4) __builtin_amdgcn_s_sleep(1);
        else            __builtin_amdgcn_s_sleep(2);
        v = __hip_atomic_load(myfl, __ATOMIC_RELAXED, __HIP_MEMORY_SCOPE_AGENT);
      }
      asm volatile("" ::: "memory");
      // ---- one bulk load pass (flags are ack-gated: data valid), then MFMA
      const u64* hp = (const u64*)hin + (size_t)rA * 128 + (kq - 2) * 64 + l4 * 2;
      u64 w[16];
#pragma unroll
      for (int ks = 0; ks < 8; ++ks) {
        w[ks * 2]     = __hip_atomic_load(hp + ks * 8,     __ATOMIC_RELAXED, __HIP_MEMORY_SCOPE_AGENT);
        w[ks * 2 + 1] = __hip_atomic_load(hp + ks * 8 + 1, __ATOMIC_RELAXED, __HIP_MEMORY_SCOPE_AGENT);
      }
#pragma unroll
      for (int ks = 0; ks < 8; ++ks) {
        union { bf16x8 v; unsigned u[4]; } fa;
        fa.u[0] = (unsigned)w[ks * 2];
        fa.u[1] = (unsigned)(w[ks * 2] >> 32);
        fa.u[2] = (unsigned)w[ks * 2 + 1];
        fa.u[3] = (unsigned)(w[ks * 2 + 1] >> 32);
#pragma unroll
        for (int g = 0; g < 4; ++g)
          acc[g] = __builtin_amdgcn_mfma_f32_16x16x32_bf16(fa.v, bfr[g][ks], acc[g], 0, 0, 0);
      }
    }
    // (kq>=2, t==0: h_{-1}=0 -> acc stays 0)

    // ---- partials to parity LDS slot (one ds_write_b128 per gate);
    //      kq2 keeps its partial in registers
    if (kq != 2) {
      const int slot = (kq == 3) ? 2 : kq;
#pragma unroll
      for (int g = 0; g < 4; ++g)
        part[tp][slot][jh][g][l4][l15] = acc[g];
    }
    asm volatile("s_waitcnt lgkmcnt(0)" ::: "memory");
    __builtin_amdgcn_s_barrier();               // raw barrier: no vmcnt drain

    // ---- phase B: kq2 waves finalize; others run ahead into t+1
    if (kq == 2) {
#pragma unroll
      for (int g = 0; g < 4; ++g)
        acc[g] += part[tp][0][jh][g][l4][l15]
                + part[tp][1][jh][g][l4][l15]
                + part[tp][2][jh][g][l4][l15];
      unsigned hw[4];
#pragma unroll
      for (int r = 0; r < 4; ++r) {
        float iv = acc[0][r] + bi, fv = acc[1][r] + bf_;
        float ov = acc[2][r] + bo, gv = acc[3][r] + bg;
        float cn = sigm(fv) * c_reg[r] + sigm(iv) * tanh_(gv);
        c_reg[r] = cn;
        hw[r] = (unsigned)(unsigned short)f2bf(sigm(ov) * tanh_(cn));
      }
#pragma unroll
      for (int r = 0; r < 4; ++r) {
        unsigned other = (unsigned)__shfl_xor((int)hw[r], 1, 64);
        if (!(l15 & 1)) {
          const int R = mg * 16 + l4 * 4 + r;
          __hip_atomic_store(hout + (size_t)R * 256 + (J >> 1),
                             hw[r] | (other << 16),
                             __ATOMIC_RELAXED, __HIP_MEMORY_SCOPE_AGENT);
        }
      }
      // ACK then flag: readers that see the flag see the data (R10 protocol).
      asm volatile("s_waitcnt vmcnt(0)" ::: "memory");
      if (lane == 0)
        __hip_atomic_store(fl + (jh * 16 + jt) * 32, (unsigned)(t + 1),
                           __ATOMIC_RELAXED, __HIP_MEMORY_SCOPE_AGENT);
    }
  }
}

// ---- out[b,:] = normalize( h_last[b,:] @ fcW + fcb ); h packed u32{2xbf16}.
// 4 rows per block (64 blocks): fcW read once per 4 rows.
__global__ __launch_bounds__(256) void final_fc(const unsigned* __restrict__ h,
                                                const float* __restrict__ fcW,
                                                const float* __restrict__ fcb,
                                                float* __restrict__ out) {
  const int b0 = blockIdx.x * 4, tid = threadIdx.x;
  __shared__ float hrow[4][512];
  __shared__ float red[4][256];
  for (int i = tid; i < 1024; i += 256) {
    unsigned w = h[(size_t)(b0 + (i >> 8)) * 256 + (i & 255)];
    hrow[i >> 8][(i & 255) * 2]     = bf2f((short)(w & 0xFFFF));
    hrow[i >> 8][(i & 255) * 2 + 1] = bf2f((short)(w >> 16));
  }
  __syncthreads();
  float a0[4], a1[4];
#pragma unroll
  for (int r = 0; r < 4; ++r) { a0[r] = fcb[tid]; a1[r] = fcb[tid + 256]; }
  for (int k = 0; k < 512; ++k) {
    const float w0 = fcW[(size_t)k * 512 + tid];
    const float w1 = fcW[(size_t)k * 512 + tid + 256];
#pragma unroll
    for (int r = 0; r < 4; ++r) {
      a0[r] += hrow[r][k] * w0;
      a1[r] += hrow[r][k] * w1;
    }
  }
#pragma unroll
  for (int r = 0; r < 4; ++r) red[r][tid] = a0[r] * a0[r] + a1[r] * a1[r];
  __syncthreads();
  for (int s = 128; s > 0; s >>= 1) {
    if (tid < s) {
#pragma unroll
      for (int r = 0; r < 4; ++r) red[r][tid] += red[r][tid + s];
    }
    __syncthreads();
  }
#pragma unroll
  for (int r = 0; r < 4; ++r) {
    const float scale = 1.0f / fmaxf(sqrtf(red[r][0]), 1e-12f);
    out[(size_t)(b0 + r) * 512 + tid]       = a0[r] * scale;
    out[(size_t)(b0 + r) * 512 + tid + 256] = a1[r] * scale;
  }
}

extern "C" void kernel_launch(void* const* d_in, const int* in_sizes, int n_in,
                              void* d_out, int out_size, void* d_ws, size_t ws_size,
                              hipStream_t stream) {
  const int*   captions = (const int*)d_in[0];
  const float* emb      = (const float*)d_in[1];
  const float* Wx       = (const float*)d_in[2];
  const float* bx       = (const float*)d_in[3];
  const float* Uh       = (const float*)d_in[4];
  const float* bu       = (const float*)d_in[5];
  const float* fcW      = (const float*)d_in[6];
  const float* fcb      = (const float*)d_in[7];
  float* out = (float*)d_out;

  char* ws = (char*)d_ws;
  size_t off = 0;
  auto alloc = [&](size_t bytes) {
    char* p = ws + off;
    off += (bytes + 255) & ~(size_t)255;
    return p;
  };
  short*    Wt    = (short*)alloc((size_t)NG * 1024 * 2);     // 4 MB
  short*    xs    = (short*)alloc((size_t)T_ * B_ * E_ * 2);  // 32 MB
  unsigned* hb0   = (unsigned*)alloc((size_t)B_ * 256 * 4);   // 256 KB packed
  unsigned* hb1   = (unsigned*)alloc((size_t)B_ * 256 * 4);
  unsigned* flags = (unsigned*)alloc(16 * 2 * 16 * 32 * 4);   // 64 KB strided

  // flags gate all h reads -> zero every launch (graph replay safe)
  hipMemsetAsync(flags, 0, 16 * 2 * 16 * 32 * 4, stream);

  prologue<<<2560, 256, 0, stream>>>(Wx, Uh, captions, emb, Wt, xs);

  void* kargs[] = {(void*)&xs, (void*)&Wt, (void*)&bx, (void*)&bu,
                   (void*)&hb0, (void*)&hb1, (void*)&flags};
  hipLaunchCooperativeKernel((const void*)lstm_all, dim3(NB), dim3(NT),
                             kargs, 0, stream);

  // t=127 wrote buffer 127&1 = hb1
  final_fc<<<64, 256, 0, stream>>>(hb1, fcW, fcb, out);
}